// Round 1
// baseline (247.156 us; speedup 1.0000x reference)
//
#include <hip/hip_runtime.h>
#include <cstdint>

#define BB 4
#define RR 512
#define CC 80
#define KK 100
#define NMS_TH 0.3f
#define SCORE_TH 0.1f
#define DWH_CLIP 4.135166556742356f

typedef unsigned int u32;
typedef unsigned long long u64;

__device__ __forceinline__ u32 f32_sortable(float f) {
  u32 u = __float_as_uint(f);
  u32 mask = (u32)((int)u >> 31) | 0x80000000u;
  return u ^ mask;
}
__device__ __forceinline__ float sortable_to_f32(u32 s) {
  u32 u = (s & 0x80000000u) ? (s ^ 0x80000000u) : ~s;
  return __uint_as_float(u);
}

// Kernel 1: one block per (image, class). Decode, stable sort by score desc,
// build suppression bitmask (column-major), greedy-NMS ballot scan, emit
// first <=100 kept candidates (key + box) to workspace.
__global__ __launch_bounds__(256) void nms_per_class(
    const float* __restrict__ rois,     // [B,R,4]
    const float* __restrict__ scores,   // [B*R, C+1]
    const float* __restrict__ deltas,   // [B*R, (C+1)*4]
    const int*   __restrict__ im_hw,    // [B,2] (h,w)
    u64*   __restrict__ cand_key,       // [B*C, K]
    float4* __restrict__ cand_box)      // [B*C, K]
{
#pragma clang fp contract(off)
  const int bc = blockIdx.x;
  const int b = bc / CC, c = bc % CC;
  const int tid = threadIdx.x;
  const int lane = tid & 63, wv = tid >> 6;

  __shared__ float4 box_o[RR];
  __shared__ float  sco_o[RR];
  __shared__ float4 box_s[RR];
  __shared__ float  sco_s[RR];
  __shared__ float  area_s[RR];
  __shared__ u64    keyarr[RR];
  __shared__ u64    colmask[8 * RR];   // [w][j]: bit i => box (64w+i) suppresses box j (64w+i<j)
  __shared__ int    klist[KK];
  __shared__ int    nkept_s;

  const float fh = (float)im_hw[b * 2 + 0] - 1.0f;  // H-1 (y clip)
  const float fw = (float)im_hw[b * 2 + 1] - 1.0f;  // W-1 (x clip)

  // ---- Phase A: decode boxes for this class, build sort keys ----
  for (int r = tid; r < RR; r += 256) {
    const float4 roi = *(const float4*)&rois[(b * RR + r) * 4];
    const int base = (b * RR + r) * (CC + 1) + (c + 1);
    const float sc = scores[base];
    const float4 d = *(const float4*)&deltas[base * 4];

    float w  = roi.z - roi.x;
    float h  = roi.w - roi.y;
    float cx = roi.x + 0.5f * w;
    float cy = roi.y + 0.5f * h;
    float dw = fminf(d.z, DWH_CLIP);
    float dh = fminf(d.w, DWH_CLIP);
    float pcx = d.x * w + cx;           // mul then add (no fma; contract off)
    float pcy = d.y * h + cy;
    float pw = w * expf(dw);
    float ph = h * expf(dh);
    float hx = 0.5f * pw, hy = 0.5f * ph;
    float x1 = fminf(fmaxf(pcx - hx, 0.0f), fw);
    float y1 = fminf(fmaxf(pcy - hy, 0.0f), fh);
    float x2 = fminf(fmaxf(pcx + hx, 0.0f), fw);
    float y2 = fminf(fmaxf(pcy + hy, 0.0f), fh);

    box_o[r] = make_float4(x1, y1, x2, y2);
    sco_o[r] = sc;
    keyarr[r] = ((u64)(~f32_sortable(sc)) << 32) | (u32)r;  // score desc, idx asc
  }
  __syncthreads();

  // ---- Phase B: bitonic sort of 512 keys, ascending ----
  for (u32 kk = 2; kk <= RR; kk <<= 1) {
    for (u32 j = kk >> 1; j > 0; j >>= 1) {
      for (u32 t = tid; t < RR; t += 256) {
        u32 ixj = t ^ j;
        if (ixj > t) {
          u64 a = keyarr[t], b2 = keyarr[ixj];
          bool up = ((t & kk) == 0);
          bool sw = up ? (a > b2) : (a < b2);
          if (sw) { keyarr[t] = b2; keyarr[ixj] = a; }
        }
      }
      __syncthreads();
    }
  }

  // gather into sorted order
  for (int p = tid; p < RR; p += 256) {
    int r = (int)(keyarr[p] & 0xFFFFFFFFull);
    float4 bx = box_o[r];
    box_s[p] = bx;
    sco_s[p] = sco_o[r];
    area_s[p] = (bx.z - bx.x) * (bx.w - bx.y);
  }
  __syncthreads();

  // ---- Phase C: suppression bitmask, column-major. Wave wv handles row-chunks
  // w = wv and w = 7-wv (balanced). Lanes = 64 columns, loop 64 rows. ----
  for (int sel = 0; sel < 2; ++sel) {
    const int w = sel ? (7 - wv) : wv;
    const int rbase = w * 64;
    for (int jb = w; jb < 8; ++jb) {       // only jb>=w can have bits (need row<j)
      const int j = jb * 64 + lane;
      const float4 bj = box_s[j];
      const float  aj = area_s[j];
      u64 word = 0;
      #pragma unroll 4
      for (int i = 0; i < 64; ++i) {
        const int row = rbase + i;
        const float4 bi = box_s[row];      // wave-uniform broadcast read
        const float  ai = area_s[row];
        float ltx = fmaxf(bi.x, bj.x);
        float lty = fmaxf(bi.y, bj.y);
        float rbx = fminf(bi.z, bj.z);
        float rby = fminf(bi.w, bj.w);
        float iw = fmaxf(rbx - ltx, 0.0f);
        float ih = fmaxf(rby - lty, 0.0f);
        float inter = iw * ih;
        float denom = ((ai + aj) - inter) + 1e-9f;   // exact ref op order
        float q = inter / denom;                     // IEEE divide, matches np
        bool pred = (q > NMS_TH) && (row < j);
        word |= pred ? (1ull << i) : 0ull;
      }
      colmask[w * RR + j] = word;
    }
  }
  __syncthreads();

  // ---- Phase D: greedy NMS scan (wave 0), 8 chunks of 64 ----
  if (wv == 0) {
    u64 kall[8];
    int nk = 0;
    #pragma unroll
    for (int w = 0; w < 8; ++w) {
      const int j = w * 64 + lane;
      const u64 mycol = colmask[w * RR + j];
      u64 pres = 0;
      #pragma unroll
      for (int w2 = 0; w2 < 8; ++w2) {
        if (w2 < w) pres |= colmask[w2 * RR + j] & kall[w2];
      }
      u64 sup = __ballot(pres != 0);
      const u64 ok = __ballot(sco_s[j] > SCORE_TH);
      u64 keepm = 0;
      for (int i = 0; i < 64; ++i) {
        if ((!((sup >> i) & 1ull)) && ((ok >> i) & 1ull)) {
          keepm |= (1ull << i);
          sup |= __ballot((mycol >> i) & 1ull);      // suppress later in-chunk
        }
      }
      kall[w] = keepm;
      if ((keepm >> lane) & 1ull) {
        int rank = nk + __popcll(keepm & ((1ull << lane) - 1ull));
        if (rank < KK) klist[rank] = j;
      }
      nk += __popcll(keepm);
    }
    if (lane == 0) nkept_s = nk;
  }
  __syncthreads();

  // ---- Phase E: emit first <=100 kept candidates (every slot written) ----
  const int nk = min(nkept_s, KK);
  for (int k = tid; k < KK; k += 256) {
    u64 kv; float4 bx;
    if (k < nk) {
      const int i = klist[k];
      const float s = sco_s[i];
      kv = ((u64)(~f32_sortable(s)) << 32) | ((u64)(u32)c << 16) | (u32)k;
      bx = box_s[i];
    } else {
      kv = ~0ull;
      bx = make_float4(0.f, 0.f, 0.f, 0.f);
    }
    cand_key[bc * KK + k] = kv;
    cand_box[bc * KK + k] = bx;
  }
}

// Kernel 2: one block per image. Sort 8192 candidate keys (8000 real + pad),
// take first 100, write [K,6] rows.
__global__ __launch_bounds__(1024) void topk_merge(
    const u64* __restrict__ cand_key,    // [B, C*K]
    const float4* __restrict__ cand_box, // [B*C, K]
    float* __restrict__ out)             // [B, K, 6]
{
  const int b = blockIdx.x;
  const int tid = threadIdx.x;
  const int N = CC * KK;                 // 8000
  const int NP = 8192;
  __shared__ u64 keys[8192];

  for (int e = tid; e < NP; e += 1024)
    keys[e] = (e < N) ? cand_key[b * N + e] : ~0ull;
  __syncthreads();

  for (u32 kk = 2; kk <= (u32)NP; kk <<= 1) {
    for (u32 j = kk >> 1; j > 0; j >>= 1) {
      for (u32 t = tid; t < (u32)NP; t += 1024) {
        u32 ixj = t ^ j;
        if (ixj > t) {
          u64 a = keys[t], b2 = keys[ixj];
          bool up = ((t & kk) == 0);
          bool sw = up ? (a > b2) : (a < b2);
          if (sw) { keys[t] = b2; keys[ixj] = a; }
        }
      }
      __syncthreads();
    }
  }

  if (tid < KK) {
    const u64 kv = keys[tid];
    float x1 = 0.f, y1 = 0.f, x2 = 0.f, y2 = 0.f, s = 0.f, cf = -1.0f;
    if (kv != ~0ull) {
      u32 inv = (u32)(kv >> 32);
      s = sortable_to_f32(~inv);
      int c = (int)((kv >> 16) & 0xFFFFull);
      int k = (int)(kv & 0xFFFFull);
      float4 bx = cand_box[(b * CC + c) * KK + k];
      x1 = bx.x; y1 = bx.y; x2 = bx.z; y2 = bx.w;
      cf = (float)c;
    }
    float* o = out + (b * KK + tid) * 6;
    o[0] = x1; o[1] = y1; o[2] = x2; o[3] = y2; o[4] = s; o[5] = cf;
  }
}

extern "C" void kernel_launch(void* const* d_in, const int* in_sizes, int n_in,
                              void* d_out, int out_size, void* d_ws, size_t ws_size,
                              hipStream_t stream) {
  (void)in_sizes; (void)n_in; (void)out_size; (void)ws_size;
  const float* rois   = (const float*)d_in[0];   // batch_rois [B,R,4]
  const float* scores = (const float*)d_in[1];   // bbox_score [B*R, C+1,1,1]
  const float* deltas = (const float*)d_in[2];   // bbox_deltas [B*R,(C+1)*4,1,1]
  const int*   im_hw  = (const int*)d_in[3];     // [B,1,1,2]

  // workspace: keys [B*C*K] u64 (256000 B), then boxes [B*C*K] float4 (512000 B)
  u64* cand_key = (u64*)d_ws;
  float4* cand_box = (float4*)((char*)d_ws + (size_t)BB * CC * KK * sizeof(u64));

  nms_per_class<<<BB * CC, 256, 0, stream>>>(rois, scores, deltas, im_hw,
                                             cand_key, cand_box);
  topk_merge<<<BB, 1024, 0, stream>>>(cand_key, cand_box, (float*)d_out);
}

// Round 2
// 139.049 us; speedup vs baseline: 1.7775x; 1.7775x over previous
//
#include <hip/hip_runtime.h>
#include <cstdint>

#define BB 4
#define RR 512
#define CC 80
#define KK 100
#define NMS_TH 0.3f
#define SCORE_TH 0.1f
#define DWH_CLIP 4.135166556742356f

typedef unsigned short u16;
typedef unsigned int u32;
typedef unsigned long long u64;

__device__ __forceinline__ u32 f32_sortable(float f) {
  u32 u = __float_as_uint(f);
  u32 mask = (u32)((int)u >> 31) | 0x80000000u;
  return u ^ mask;
}
__device__ __forceinline__ float sortable_to_f32(u32 s) {
  u32 u = (s & 0x80000000u) ? (s ^ 0x80000000u) : ~s;
  return __uint_as_float(u);
}

// Kernel 1: one block per (image, class). Score-sort, decode in sorted order,
// build suppression bitmask (column-major), greedy-NMS ballot scan, emit
// first <=100 kept candidates (key + box) to workspace. Pad slots get unique
// keys encoding score = -1e9 (reference NEG) so all 8000 keys are distinct.
__global__ __launch_bounds__(256) void nms_per_class(
    const float* __restrict__ rois,     // [B,R,4]
    const float* __restrict__ scores,   // [B*R, C+1]
    const float* __restrict__ deltas,   // [B*R, (C+1)*4]
    const int*   __restrict__ im_hw,    // [B,2] (h,w)
    u64*   __restrict__ cand_key,       // [B*C, K]
    float4* __restrict__ cand_box)      // [B*C, K]
{
#pragma clang fp contract(off)
  const int bc = blockIdx.x;
  const int b = bc / CC, c = bc % CC;
  const int tid = threadIdx.x;
  const int lane = tid & 63, wv = tid >> 6;

  __shared__ float4 box_s[RR];          // 8 KB
  __shared__ float  sco_s[RR];          // 2 KB
  __shared__ float  area_s[RR];         // 2 KB
  __shared__ u64    keyarr[RR];         // 4 KB
  __shared__ u64    colmask[8 * RR];    // 32 KB  [w][j]: bit i => box 64w+i suppresses j
  __shared__ int    klist[KK];
  __shared__ int    nkept_s;

  const float fh = (float)im_hw[b * 2 + 0] - 1.0f;
  const float fw = (float)im_hw[b * 2 + 1] - 1.0f;

  // ---- Phase A: score sort keys only ----
  for (int r = tid; r < RR; r += 256) {
    const float sc = scores[(b * RR + r) * (CC + 1) + (c + 1)];
    keyarr[r] = ((u64)(~f32_sortable(sc)) << 32) | (u32)r;  // score desc, idx asc
  }
  __syncthreads();

  // ---- Phase B: bitonic sort of 512 keys, ascending ----
  for (u32 kk = 2; kk <= RR; kk <<= 1) {
    for (u32 j = kk >> 1; j > 0; j >>= 1) {
      for (u32 t = tid; t < RR; t += 256) {
        u32 ixj = t ^ j;
        if (ixj > t) {
          u64 a = keyarr[t], b2 = keyarr[ixj];
          bool up = ((t & kk) == 0);
          bool sw = up ? (a > b2) : (a < b2);
          if (sw) { keyarr[t] = b2; keyarr[ixj] = a; }
        }
      }
      __syncthreads();
    }
  }

  // ---- gather + decode into sorted order ----
  for (int p = tid; p < RR; p += 256) {
    const int r = (int)(keyarr[p] & 0xFFFFFFFFull);
    const float4 roi = *(const float4*)&rois[(b * RR + r) * 4];
    const int base = (b * RR + r) * (CC + 1) + (c + 1);
    const float sc = scores[base];
    const float4 d = *(const float4*)&deltas[base * 4];

    float w  = roi.z - roi.x;
    float h  = roi.w - roi.y;
    float cx = roi.x + 0.5f * w;
    float cy = roi.y + 0.5f * h;
    float dw = fminf(d.z, DWH_CLIP);
    float dh = fminf(d.w, DWH_CLIP);
    float pcx = d.x * w + cx;
    float pcy = d.y * h + cy;
    float pw = w * expf(dw);
    float ph = h * expf(dh);
    float hx = 0.5f * pw, hy = 0.5f * ph;
    float x1 = fminf(fmaxf(pcx - hx, 0.0f), fw);
    float y1 = fminf(fmaxf(pcy - hy, 0.0f), fh);
    float x2 = fminf(fmaxf(pcx + hx, 0.0f), fw);
    float y2 = fminf(fmaxf(pcy + hy, 0.0f), fh);

    box_s[p] = make_float4(x1, y1, x2, y2);
    sco_s[p] = sc;
    area_s[p] = (x2 - x1) * (y2 - y1);
  }
  __syncthreads();

  // ---- Phase C: suppression bitmask, column-major ----
  for (int sel = 0; sel < 2; ++sel) {
    const int w = sel ? (7 - wv) : wv;
    const int rbase = w * 64;
    for (int jb = w; jb < 8; ++jb) {
      const int j = jb * 64 + lane;
      const float4 bj = box_s[j];
      const float  aj = area_s[j];
      u64 word = 0;
      #pragma unroll 4
      for (int i = 0; i < 64; ++i) {
        const int row = rbase + i;
        const float4 bi = box_s[row];
        const float  ai = area_s[row];
        float ltx = fmaxf(bi.x, bj.x);
        float lty = fmaxf(bi.y, bj.y);
        float rbx = fminf(bi.z, bj.z);
        float rby = fminf(bi.w, bj.w);
        float iw = fmaxf(rbx - ltx, 0.0f);
        float ih = fmaxf(rby - lty, 0.0f);
        float inter = iw * ih;
        float denom = ((ai + aj) - inter) + 1e-9f;   // exact ref op order
        float q = inter / denom;
        bool pred = (q > NMS_TH) && (row < j);
        word |= pred ? (1ull << i) : 0ull;
      }
      colmask[w * RR + j] = word;
    }
  }
  __syncthreads();

  // ---- Phase D: greedy NMS scan (wave 0) ----
  if (wv == 0) {
    u64 kall[8];
    int nk = 0;
    #pragma unroll
    for (int w = 0; w < 8; ++w) {
      const int j = w * 64 + lane;
      const u64 mycol = colmask[w * RR + j];
      u64 pres = 0;
      #pragma unroll
      for (int w2 = 0; w2 < 8; ++w2) {
        if (w2 < w) pres |= colmask[w2 * RR + j] & kall[w2];
      }
      u64 sup = __ballot(pres != 0);
      const u64 ok = __ballot(sco_s[j] > SCORE_TH);
      u64 keepm = 0;
      for (int i = 0; i < 64; ++i) {
        if ((!((sup >> i) & 1ull)) && ((ok >> i) & 1ull)) {
          keepm |= (1ull << i);
          sup |= __ballot((mycol >> i) & 1ull);
        }
      }
      kall[w] = keepm;
      if ((keepm >> lane) & 1ull) {
        int rank = nk + __popcll(keepm & ((1ull << lane) - 1ull));
        if (rank < KK) klist[rank] = j;
      }
      nk += __popcll(keepm);
    }
    if (lane == 0) nkept_s = nk;
  }
  __syncthreads();

  // ---- Phase E: emit (every slot written; pads unique, score = -1e9) ----
  const int nk = min(nkept_s, KK);
  for (int k = tid; k < KK; k += 256) {
    u64 kv; float4 bx;
    if (k < nk) {
      const int i = klist[k];
      kv = ((u64)(~f32_sortable(sco_s[i])) << 32) | ((u64)(u32)c << 16) | (u32)k;
      bx = box_s[i];
    } else {
      kv = ((u64)(~f32_sortable(-1e9f)) << 32) | ((u64)(u32)c << 16) | (u32)k;
      bx = make_float4(0.f, 0.f, 0.f, 0.f);
    }
    cand_key[bc * KK + k] = kv;
    cand_box[bc * KK + k] = bx;
  }
}

// Kernel 2: one block per image. Radix-select the rank-99 key T over the 8000
// (unique) candidate keys, gather the exactly-100 keys <= T, bitonic-sort 128,
// write [K,6] rows.
__global__ __launch_bounds__(1024) void topk_select(
    const u64* __restrict__ cand_key,    // [B, C*K]
    const float4* __restrict__ cand_box, // [B*C, K]
    float* __restrict__ out)             // [B, K, 6]
{
  const int b = blockIdx.x;
  const int tid = threadIdx.x;
  const int lane = tid & 63, wv = tid >> 6;
  const int N = CC * KK;                 // 8000
  const u64* __restrict__ keys_g = cand_key + (size_t)b * N;

  __shared__ u16 candA[CC * KK];         // 16 KB
  __shared__ u16 candB[CC * KK];         // 16 KB
  __shared__ u32 bins[256];
  __shared__ u64 smallkeys[128];
  __shared__ int ncand_s, rank_s, q_s;
  __shared__ u32 cnt_s;

  for (int t = tid; t < N; t += 1024) candA[t] = (u16)t;
  if (tid == 0) { ncand_s = N; rank_s = KK - 1; }
  __syncthreads();

  u16* cur = candA;
  u16* oth = candB;
  int d = 7;
  for (;;) {
    if (tid < 256) bins[tid] = 0;
    __syncthreads();
    const int nc = ncand_s;
    const int sh = d * 8;
    for (int t = tid; t < nc; t += 1024) {
      u32 dig = (u32)((keys_g[cur[t]] >> sh) & 0xFF);
      atomicAdd(&bins[dig], 1u);
    }
    __syncthreads();
    if (wv == 0) {
      u32 c0 = bins[lane * 4 + 0], c1 = bins[lane * 4 + 1];
      u32 c2 = bins[lane * 4 + 2], c3 = bins[lane * 4 + 3];
      u32 lsum = c0 + c1 + c2 + c3;
      u32 incl = lsum;
      #pragma unroll
      for (int off = 1; off < 64; off <<= 1) {
        u32 v = __shfl_up(incl, off);
        if (lane >= off) incl += v;
      }
      u32 excl = incl - lsum;
      int rk = rank_s;
      u32 s0 = excl, s1 = excl + c0, s2 = s1 + c1, s3 = s2 + c2;
      int q = -1; u32 nr = 0;
      if (rk >= (int)s0 && rk < (int)(s0 + c0)) { q = lane * 4 + 0; nr = rk - s0; }
      else if (rk >= (int)s1 && rk < (int)(s1 + c1)) { q = lane * 4 + 1; nr = rk - s1; }
      else if (rk >= (int)s2 && rk < (int)(s2 + c2)) { q = lane * 4 + 2; nr = rk - s2; }
      else if (rk >= (int)s3 && rk < (int)(s3 + c3)) { q = lane * 4 + 3; nr = rk - s3; }
      if (q >= 0) { q_s = q; rank_s = (int)nr; }
    }
    if (tid == 0) cnt_s = 0;
    __syncthreads();
    const int q = q_s;
    for (int t = tid; t < nc; t += 1024) {
      u32 idx = cur[t];
      u32 dig = (u32)((keys_g[idx] >> sh) & 0xFF);
      if ((int)dig == q) {
        u32 p = atomicAdd(&cnt_s, 1u);
        oth[p] = (u16)idx;
      }
    }
    __syncthreads();
    if (tid == 0) ncand_s = (int)cnt_s;
    { u16* tmp = cur; cur = oth; oth = tmp; }
    __syncthreads();
    if (ncand_s == 1 || d == 0) break;
    --d;
  }
  const u64 T = keys_g[cur[0]];   // rank-99 smallest key (keys unique)

  // gather the exactly-100 keys <= T
  if (tid == 0) cnt_s = 0;
  if (tid < 128) smallkeys[tid] = ~0ull;
  __syncthreads();
  for (int t = tid; t < N; t += 1024) {
    u64 k = keys_g[t];
    if (k <= T) {
      u32 p = atomicAdd(&cnt_s, 1u);
      if (p < 128) smallkeys[p] = k;
    }
  }
  __syncthreads();

  // bitonic sort 128
  for (u32 kk = 2; kk <= 128; kk <<= 1) {
    for (u32 j = kk >> 1; j > 0; j >>= 1) {
      if (tid < 128) {
        u32 t = tid, ixj = t ^ j;
        if (ixj > t) {
          u64 a = smallkeys[t], b2 = smallkeys[ixj];
          bool up = ((t & kk) == 0);
          bool sw = up ? (a > b2) : (a < b2);
          if (sw) { smallkeys[t] = b2; smallkeys[ixj] = a; }
        }
      }
      __syncthreads();
    }
  }

  if (tid < KK) {
    const u64 kv = smallkeys[tid];
    const float s = sortable_to_f32(~(u32)(kv >> 32));
    float x1 = 0.f, y1 = 0.f, x2 = 0.f, y2 = 0.f, so = 0.f, cf = -1.0f;
    if (s > -5.0e8f) {                   // valid = top_s > NEG*0.5
      int c = (int)((kv >> 16) & 0xFFFFull);
      int k = (int)(kv & 0xFFFFull);
      float4 bx = cand_box[((size_t)b * CC + c) * KK + k];
      x1 = bx.x; y1 = bx.y; x2 = bx.z; y2 = bx.w;
      so = s; cf = (float)c;
    }
    float* o = out + ((size_t)b * KK + tid) * 6;
    o[0] = x1; o[1] = y1; o[2] = x2; o[3] = y2; o[4] = so; o[5] = cf;
  }
}

extern "C" void kernel_launch(void* const* d_in, const int* in_sizes, int n_in,
                              void* d_out, int out_size, void* d_ws, size_t ws_size,
                              hipStream_t stream) {
  (void)in_sizes; (void)n_in; (void)out_size; (void)ws_size;
  const float* rois   = (const float*)d_in[0];
  const float* scores = (const float*)d_in[1];
  const float* deltas = (const float*)d_in[2];
  const int*   im_hw  = (const int*)d_in[3];

  u64* cand_key = (u64*)d_ws;
  float4* cand_box = (float4*)((char*)d_ws + (size_t)BB * CC * KK * sizeof(u64));

  nms_per_class<<<BB * CC, 256, 0, stream>>>(rois, scores, deltas, im_hw,
                                             cand_key, cand_box);
  topk_select<<<BB, 1024, 0, stream>>>(cand_key, cand_box, (float*)d_out);
}

// Round 3
// 102.704 us; speedup vs baseline: 2.4065x; 1.3539x over previous
//
#include <hip/hip_runtime.h>
#include <cstdint>

#define BB 4
#define RR 512
#define CC 80
#define KK 100
#define NMS_TH 0.3f
#define SCORE_TH 0.1f
#define DWH_CLIP 4.135166556742356f

typedef unsigned short u16;
typedef unsigned int u32;
typedef unsigned long long u64;

__device__ __forceinline__ u32 f32_sortable(float f) {
  u32 u = __float_as_uint(f);
  u32 mask = (u32)((int)u >> 31) | 0x80000000u;
  return u ^ mask;
}
__device__ __forceinline__ float sortable_to_f32(u32 s) {
  u32 u = (s & 0x80000000u) ? (s ^ 0x80000000u) : ~s;
  return __uint_as_float(u);
}

// Kernel 1: one block of 512 per (image, class).
__global__ __launch_bounds__(512) void nms_per_class(
    const float* __restrict__ rois,     // [B,R,4]
    const float* __restrict__ scores,   // [B*R, C+1]
    const float* __restrict__ deltas,   // [B*R, (C+1)*4]
    const int*   __restrict__ im_hw,    // [B,2] (h,w)
    u64*   __restrict__ cand_key,       // [B*C, K]
    float4* __restrict__ cand_box)      // [B*C, K]
{
#pragma clang fp contract(off)
  const int bc = blockIdx.x;
  const int b = bc / CC, c = bc % CC;
  const int tid = threadIdx.x;
  const int lane = tid & 63, wv = tid >> 6;

  __shared__ float4 box_s[RR];          // 8 KB
  __shared__ float  sco_s[RR];          // 2 KB
  __shared__ float  area_s[RR];         // 2 KB
  __shared__ u64    keyarr[RR];         // 4 KB
  __shared__ u64    colmask[8 * RR];    // 32 KB
  __shared__ int    klist[KK];
  __shared__ int    nkept_s;

  const float fh = (float)im_hw[b * 2 + 0] - 1.0f;
  const float fw = (float)im_hw[b * 2 + 1] - 1.0f;

  // ---- Phase A+B: per-thread key, hybrid bitonic sort (512 elems, 512 thr) ----
  {
    const float sc = scores[(b * RR + tid) * (CC + 1) + (c + 1)];
    u64 v = ((u64)(~f32_sortable(sc)) << 32) | (u32)tid;  // score desc, idx asc
    const u32 t = (u32)tid;
    for (u32 kk = 2; kk <= RR; kk <<= 1) {
      for (u32 j = kk >> 1; j > 0; j >>= 1) {
        u64 p;
        if (j >= 64) {
          keyarr[t] = v;
          __syncthreads();
          p = keyarr[t ^ j];
          __syncthreads();
        } else {
          p = __shfl_xor(v, (int)j);
        }
        bool up = ((t & kk) == 0);
        bool lower = ((t & j) == 0);
        bool takemin = (up == lower);
        bool pless = (p < v);
        v = (takemin == pless) ? p : v;
      }
    }
    keyarr[t] = v;
  }
  __syncthreads();

  // ---- gather + decode into sorted order (1 elem/thread) ----
  {
    const int p = tid;
    const u64 kv = keyarr[p];
    const int r = (int)(kv & 0xFFFFFFFFull);
    const float sc = sortable_to_f32(~(u32)(kv >> 32));   // bit-exact original
    const float4 roi = *(const float4*)&rois[(b * RR + r) * 4];
    const int base = (b * RR + r) * (CC + 1) + (c + 1);
    const float4 d = *(const float4*)&deltas[base * 4];

    float w  = roi.z - roi.x;
    float h  = roi.w - roi.y;
    float cx = roi.x + 0.5f * w;
    float cy = roi.y + 0.5f * h;
    float dw = fminf(d.z, DWH_CLIP);
    float dh = fminf(d.w, DWH_CLIP);
    float pcx = d.x * w + cx;
    float pcy = d.y * h + cy;
    float pw = w * expf(dw);
    float ph = h * expf(dh);
    float hx = 0.5f * pw, hy = 0.5f * ph;
    float x1 = fminf(fmaxf(pcx - hx, 0.0f), fw);
    float y1 = fminf(fmaxf(pcy - hy, 0.0f), fh);
    float x2 = fminf(fmaxf(pcx + hx, 0.0f), fw);
    float y2 = fminf(fmaxf(pcy + hy, 0.0f), fh);

    box_s[p] = make_float4(x1, y1, x2, y2);
    sco_s[p] = sc;
    area_s[p] = (x2 - x1) * (y2 - y1);
  }
  __syncthreads();

  // ---- Phase C: suppression bitmask, tiles round-robined over 8 waves ----
  {
    int tc = 0;
    for (int w = 0; w < 8; ++w) {
      const int rbase = w * 64;
      for (int jb = w; jb < 8; ++jb) {
        if ((tc++ & 7) != wv) continue;
        const int j = jb * 64 + lane;
        const float4 bj = box_s[j];
        const float  aj = area_s[j];
        u64 word = 0;
        #pragma unroll 4
        for (int i = 0; i < 64; ++i) {
          const int row = rbase + i;
          const float4 bi = box_s[row];
          const float  ai = area_s[row];
          float ltx = fmaxf(bi.x, bj.x);
          float lty = fmaxf(bi.y, bj.y);
          float rbx = fminf(bi.z, bj.z);
          float rby = fminf(bi.w, bj.w);
          float iw = fmaxf(rbx - ltx, 0.0f);
          float ih = fmaxf(rby - lty, 0.0f);
          float inter = iw * ih;
          float denom = ((ai + aj) - inter) + 1e-9f;   // exact ref op order
          float q = inter / denom;
          bool pred = (q > NMS_TH) && (row < j);
          word |= pred ? (1ull << i) : 0ull;
        }
        colmask[w * RR + j] = word;
      }
    }
  }
  __syncthreads();

  // ---- Phase D: greedy NMS scan (wave 0), sparse over kept boxes ----
  if (wv == 0) {
    u64 kall[8];
    int nk = 0;
    #pragma unroll
    for (int w = 0; w < 8; ++w) {
      const int j = w * 64 + lane;
      const u64 mycol = colmask[w * RR + j];
      u64 pres = 0;
      #pragma unroll
      for (int w2 = 0; w2 < 8; ++w2) {
        if (w2 < w) pres |= colmask[w2 * RR + j] & kall[w2];
      }
      u64 sup = __ballot(pres != 0);
      const u64 ok = __ballot(sco_s[j] > SCORE_TH);
      u64 keepm = 0;
      u64 todo = ok & ~sup;
      while (todo) {
        const int i = __ffsll((long long)todo) - 1;   // highest-score remaining
        keepm |= (1ull << i);
        sup |= __ballot((mycol >> i) & 1ull);
        todo &= ~(sup | (1ull << i));
      }
      kall[w] = keepm;
      if ((keepm >> lane) & 1ull) {
        int rank = nk + __popcll(keepm & ((1ull << lane) - 1ull));
        if (rank < KK) klist[rank] = j;
      }
      nk += __popcll(keepm);
    }
    if (lane == 0) nkept_s = nk;
  }
  __syncthreads();

  // ---- Phase E: emit (pads unique, score = -1e9 = reference NEG) ----
  const int nk = min(nkept_s, KK);
  if (tid < KK) {
    const int k = tid;
    u64 kv; float4 bx;
    if (k < nk) {
      const int i = klist[k];
      kv = ((u64)(~f32_sortable(sco_s[i])) << 32) | ((u64)(u32)c << 16) | (u32)k;
      bx = box_s[i];
    } else {
      kv = ((u64)(~f32_sortable(-1e9f)) << 32) | ((u64)(u32)c << 16) | (u32)k;
      bx = make_float4(0.f, 0.f, 0.f, 0.f);
    }
    cand_key[bc * KK + k] = kv;
    cand_box[bc * KK + k] = bx;
  }
}

// Kernel 2: one block per image. Radix-select rank-99 key T over 8000 unique
// keys, gather the exactly-100 keys <= T, hybrid-sort 128, write [K,6].
__global__ __launch_bounds__(1024) void topk_select(
    const u64* __restrict__ cand_key,    // [B, C*K]
    const float4* __restrict__ cand_box, // [B*C, K]
    float* __restrict__ out)             // [B, K, 6]
{
  const int b = blockIdx.x;
  const int tid = threadIdx.x;
  const int lane = tid & 63, wv = tid >> 6;
  const int N = CC * KK;                 // 8000
  const u64* __restrict__ keys_g = cand_key + (size_t)b * N;

  __shared__ u16 candA[CC * KK];         // 16 KB
  __shared__ u16 candB[CC * KK];         // 16 KB
  __shared__ u32 bins[256];
  __shared__ u64 smallkeys[128];
  __shared__ int ncand_s, rank_s, q_s;
  __shared__ u32 cnt_s;

  for (int t = tid; t < N; t += 1024) candA[t] = (u16)t;
  if (tid == 0) { ncand_s = N; rank_s = KK - 1; }
  __syncthreads();

  u16* cur = candA;
  u16* oth = candB;
  int d = 7;
  for (;;) {
    if (tid < 256) bins[tid] = 0;
    __syncthreads();
    const int nc = ncand_s;
    const int sh = d * 8;
    for (int t = tid; t < nc; t += 1024) {
      u32 dig = (u32)((keys_g[cur[t]] >> sh) & 0xFF);
      atomicAdd(&bins[dig], 1u);
    }
    __syncthreads();
    if (wv == 0) {
      u32 c0 = bins[lane * 4 + 0], c1 = bins[lane * 4 + 1];
      u32 c2 = bins[lane * 4 + 2], c3 = bins[lane * 4 + 3];
      u32 lsum = c0 + c1 + c2 + c3;
      u32 incl = lsum;
      #pragma unroll
      for (int off = 1; off < 64; off <<= 1) {
        u32 v = __shfl_up(incl, off);
        if (lane >= off) incl += v;
      }
      u32 excl = incl - lsum;
      int rk = rank_s;
      u32 s0 = excl, s1 = excl + c0, s2 = s1 + c1, s3 = s2 + c2;
      int q = -1; u32 nr = 0;
      if (rk >= (int)s0 && rk < (int)(s0 + c0)) { q = lane * 4 + 0; nr = rk - s0; }
      else if (rk >= (int)s1 && rk < (int)(s1 + c1)) { q = lane * 4 + 1; nr = rk - s1; }
      else if (rk >= (int)s2 && rk < (int)(s2 + c2)) { q = lane * 4 + 2; nr = rk - s2; }
      else if (rk >= (int)s3 && rk < (int)(s3 + c3)) { q = lane * 4 + 3; nr = rk - s3; }
      if (q >= 0) { q_s = q; rank_s = (int)nr; }
    }
    if (tid == 0) cnt_s = 0;
    __syncthreads();
    const int q = q_s;
    for (int t = tid; t < nc; t += 1024) {
      u32 idx = cur[t];
      u32 dig = (u32)((keys_g[idx] >> sh) & 0xFF);
      if ((int)dig == q) {
        u32 p = atomicAdd(&cnt_s, 1u);
        oth[p] = (u16)idx;
      }
    }
    __syncthreads();
    if (tid == 0) ncand_s = (int)cnt_s;
    { u16* tmp = cur; cur = oth; oth = tmp; }
    __syncthreads();
    if (ncand_s == 1 || d == 0) break;
    --d;
  }
  const u64 T = keys_g[cur[0]];   // rank-99 smallest key (keys unique)

  // gather the exactly-100 keys <= T
  if (tid == 0) cnt_s = 0;
  if (tid < 128) smallkeys[tid] = ~0ull;
  __syncthreads();
  for (int t = tid; t < N; t += 1024) {
    u64 k = keys_g[t];
    if (k <= T) {
      u32 p = atomicAdd(&cnt_s, 1u);
      if (p < 128) smallkeys[p] = k;
    }
  }
  __syncthreads();

  // hybrid bitonic sort of 128 (2 waves; LDS only for the j=64 passes)
  {
    u64 v = (tid < 128) ? smallkeys[tid] : ~0ull;
    const u32 t = (u32)tid;
    for (u32 kk = 2; kk <= 128; kk <<= 1) {
      for (u32 j = kk >> 1; j > 0; j >>= 1) {
        if (j >= 64) {
          if (tid < 128) smallkeys[t] = v;
          __syncthreads();
          u64 p = (tid < 128) ? smallkeys[t ^ j] : ~0ull;
          __syncthreads();
          if (tid < 128) {
            bool up = ((t & kk) == 0);
            bool lower = ((t & j) == 0);
            bool takemin = (up == lower);
            bool pless = (p < v);
            v = (takemin == pless) ? p : v;
          }
        } else if (tid < 128) {
          u64 p = __shfl_xor(v, (int)j);
          bool up = ((t & kk) == 0);
          bool lower = ((t & j) == 0);
          bool takemin = (up == lower);
          bool pless = (p < v);
          v = (takemin == pless) ? p : v;
        }
      }
    }
    if (tid < KK) {
      const u64 kv = v;
      const float s = sortable_to_f32(~(u32)(kv >> 32));
      float x1 = 0.f, y1 = 0.f, x2 = 0.f, y2 = 0.f, so = 0.f, cf = -1.0f;
      if (s > -5.0e8f) {                 // valid = top_s > NEG*0.5
        int c = (int)((kv >> 16) & 0xFFFFull);
        int k = (int)(kv & 0xFFFFull);
        float4 bx = cand_box[((size_t)b * CC + c) * KK + k];
        x1 = bx.x; y1 = bx.y; x2 = bx.z; y2 = bx.w;
        so = s; cf = (float)c;
      }
      float* o = out + ((size_t)b * KK + tid) * 6;
      o[0] = x1; o[1] = y1; o[2] = x2; o[3] = y2; o[4] = so; o[5] = cf;
    }
  }
}

extern "C" void kernel_launch(void* const* d_in, const int* in_sizes, int n_in,
                              void* d_out, int out_size, void* d_ws, size_t ws_size,
                              hipStream_t stream) {
  (void)in_sizes; (void)n_in; (void)out_size; (void)ws_size;
  const float* rois   = (const float*)d_in[0];
  const float* scores = (const float*)d_in[1];
  const float* deltas = (const float*)d_in[2];
  const int*   im_hw  = (const int*)d_in[3];

  u64* cand_key = (u64*)d_ws;
  float4* cand_box = (float4*)((char*)d_ws + (size_t)BB * CC * KK * sizeof(u64));

  nms_per_class<<<BB * CC, 512, 0, stream>>>(rois, scores, deltas, im_hw,
                                             cand_key, cand_box);
  topk_select<<<BB, 1024, 0, stream>>>(cand_key, cand_box, (float*)d_out);
}

// Round 4
// 91.663 us; speedup vs baseline: 2.6963x; 1.1204x over previous
//
#include <hip/hip_runtime.h>
#include <cstdint>

#define BB 4
#define RR 512
#define CC 80
#define KK 100
#define NMS_TH 0.3f
#define SCORE_TH 0.1f
#define DWH_CLIP 4.135166556742356f

typedef unsigned short u16;
typedef unsigned int u32;
typedef unsigned long long u64;

__device__ __forceinline__ u32 f32_sortable(float f) {
  u32 u = __float_as_uint(f);
  u32 mask = (u32)((int)u >> 31) | 0x80000000u;
  return u ^ mask;
}
__device__ __forceinline__ float sortable_to_f32(u32 s) {
  u32 u = (s & 0x80000000u) ? (s ^ 0x80000000u) : ~s;
  return __uint_as_float(u);
}

// Kernel 1: one block of 512 per (image, class).
__global__ __launch_bounds__(512) void nms_per_class(
    const float* __restrict__ rois,     // [B,R,4]
    const float* __restrict__ scores,   // [B*R, C+1]
    const float* __restrict__ deltas,   // [B*R, (C+1)*4]
    const int*   __restrict__ im_hw,    // [B,2] (h,w)
    u64*   __restrict__ cand_key,       // [B*C, K]
    float4* __restrict__ cand_box)      // [B*C, K]
{
#pragma clang fp contract(off)
  const int bc = blockIdx.x;
  const int b = bc / CC, c = bc % CC;
  const int tid = threadIdx.x;
  const int lane = tid & 63, wv = tid >> 6;

  __shared__ float4 box_s[RR];          // 8 KB
  __shared__ float  sco_s[RR];          // 2 KB
  __shared__ float  area_s[RR];         // 2 KB
  __shared__ u64    keyarr[RR];         // 4 KB
  __shared__ u64    colmask[8 * RR];    // 32 KB
  __shared__ int    klist[KK];
  __shared__ int    nkept_s;

  const float fh = (float)im_hw[b * 2 + 0] - 1.0f;
  const float fw = (float)im_hw[b * 2 + 1] - 1.0f;

  // ---- Phase A+B: per-thread key, hybrid bitonic sort (512 elems, 512 thr) ----
  {
    const float sc = scores[(b * RR + tid) * (CC + 1) + (c + 1)];
    u64 v = ((u64)(~f32_sortable(sc)) << 32) | (u32)tid;  // score desc, idx asc
    const u32 t = (u32)tid;
    for (u32 kk = 2; kk <= RR; kk <<= 1) {
      for (u32 j = kk >> 1; j > 0; j >>= 1) {
        u64 p;
        if (j >= 64) {
          keyarr[t] = v;
          __syncthreads();
          p = keyarr[t ^ j];
          __syncthreads();
        } else {
          p = __shfl_xor(v, (int)j);
        }
        bool up = ((t & kk) == 0);
        bool lower = ((t & j) == 0);
        bool takemin = (up == lower);
        bool pless = (p < v);
        v = (takemin == pless) ? p : v;
      }
    }
    keyarr[t] = v;
  }
  __syncthreads();

  // ---- gather + decode into sorted order (1 elem/thread) ----
  {
    const int p = tid;
    const u64 kv = keyarr[p];
    const int r = (int)(kv & 0xFFFFFFFFull);
    const float sc = sortable_to_f32(~(u32)(kv >> 32));   // bit-exact original
    const float4 roi = *(const float4*)&rois[(b * RR + r) * 4];
    const int base = (b * RR + r) * (CC + 1) + (c + 1);
    const float4 d = *(const float4*)&deltas[base * 4];

    float w  = roi.z - roi.x;
    float h  = roi.w - roi.y;
    float cx = roi.x + 0.5f * w;
    float cy = roi.y + 0.5f * h;
    float dw = fminf(d.z, DWH_CLIP);
    float dh = fminf(d.w, DWH_CLIP);
    float pcx = d.x * w + cx;
    float pcy = d.y * h + cy;
    float pw = w * expf(dw);
    float ph = h * expf(dh);
    float hx = 0.5f * pw, hy = 0.5f * ph;
    float x1 = fminf(fmaxf(pcx - hx, 0.0f), fw);
    float y1 = fminf(fmaxf(pcy - hy, 0.0f), fh);
    float x2 = fminf(fmaxf(pcx + hx, 0.0f), fw);
    float y2 = fminf(fmaxf(pcy + hy, 0.0f), fh);

    box_s[p] = make_float4(x1, y1, x2, y2);
    sco_s[p] = sc;
    area_s[p] = (x2 - x1) * (y2 - y1);
  }
  __syncthreads();

  // ---- Phase C: suppression bitmask. Divide-free certain test + rare exact
  // fallback. Certainty margin: hi = RN(inter - 0.3f*denom) via fma (exact
  // product). hi > 1e-7*denom => exact quotient > 0.3f + 2^-27 => RN(q) > 0.3f.
  // hi < -1e-7*denom => q < 0.3f => RN(q) <= 0.3f. |hi| <= mg => exact divide.
  {
    int tc = 0;
    for (int w = 0; w < 8; ++w) {
      const int rbase = w * 64;
      for (int jb = w; jb < 8; ++jb) {
        if ((tc++ & 7) != wv) continue;
        const int j = jb * 64 + lane;
        const float4 bj = box_s[j];
        const float  aj = area_s[j];
        u64 word = 0;
        #pragma unroll 4
        for (int i = 0; i < 64; ++i) {
          const int row = rbase + i;
          const float4 bi = box_s[row];
          const float  ai = area_s[row];
          float ltx = fmaxf(bi.x, bj.x);
          float lty = fmaxf(bi.y, bj.y);
          float rbx = fminf(bi.z, bj.z);
          float rby = fminf(bi.w, bj.w);
          float iw = fmaxf(rbx - ltx, 0.0f);
          float ih = fmaxf(rby - lty, 0.0f);
          float inter = iw * ih;
          float denom = ((ai + aj) - inter) + 1e-9f;   // exact ref op order
          float hi = fmaf(-NMS_TH, denom, inter);
          float mg = 1e-7f * denom;
          bool pred = hi > mg;
          bool unc = fabsf(hi) <= mg;
          if (__any(unc)) {                            // ~never taken
            float q = inter / denom;                   // exact IEEE path
            bool pe = q > NMS_TH;
            pred = unc ? pe : pred;
          }
          word |= pred ? (1ull << i) : 0ull;
        }
        if (jb == w) word &= (1ull << lane) - 1ull;    // keep only row<j
        colmask[w * RR + j] = word;
      }
    }
  }
  __syncthreads();

  // ---- Phase D: greedy NMS scan (wave 0), sparse over kept boxes ----
  if (wv == 0) {
    u64 kall[8];
    int nk = 0;
    #pragma unroll
    for (int w = 0; w < 8; ++w) {
      const int j = w * 64 + lane;
      const u64 mycol = colmask[w * RR + j];
      u64 pres = 0;
      #pragma unroll
      for (int w2 = 0; w2 < 8; ++w2) {
        if (w2 < w) pres |= colmask[w2 * RR + j] & kall[w2];
      }
      u64 sup = __ballot(pres != 0);
      const u64 ok = __ballot(sco_s[j] > SCORE_TH);
      u64 keepm = 0;
      u64 todo = ok & ~sup;
      while (todo) {
        const int i = __ffsll((long long)todo) - 1;
        keepm |= (1ull << i);
        sup |= __ballot((mycol >> i) & 1ull);
        todo &= ~(sup | (1ull << i));
      }
      kall[w] = keepm;
      if ((keepm >> lane) & 1ull) {
        int rank = nk + __popcll(keepm & ((1ull << lane) - 1ull));
        if (rank < KK) klist[rank] = j;
      }
      nk += __popcll(keepm);
    }
    if (lane == 0) nkept_s = nk;
  }
  __syncthreads();

  // ---- Phase E: emit (pads unique, score = -1e9 = reference NEG) ----
  const int nk = min(nkept_s, KK);
  if (tid < KK) {
    const int k = tid;
    u64 kv; float4 bx;
    if (k < nk) {
      const int i = klist[k];
      kv = ((u64)(~f32_sortable(sco_s[i])) << 32) | ((u64)(u32)c << 16) | (u32)k;
      bx = box_s[i];
    } else {
      kv = ((u64)(~f32_sortable(-1e9f)) << 32) | ((u64)(u32)c << 16) | (u32)k;
      bx = make_float4(0.f, 0.f, 0.f, 0.f);
    }
    cand_key[bc * KK + k] = kv;
    cand_box[bc * KK + k] = bx;
  }
}

// Kernel 2: one block per image. Radix-select rank-99 key T over 8000 unique
// keys (wave-sliced histograms, wave-aggregated compaction), gather the
// exactly-100 keys <= T, hybrid-sort 128, write [K,6].
__global__ __launch_bounds__(1024) void topk_select(
    const u64* __restrict__ cand_key,    // [B, C*K]
    const float4* __restrict__ cand_box, // [B*C, K]
    float* __restrict__ out)             // [B, K, 6]
{
  const int b = blockIdx.x;
  const int tid = threadIdx.x;
  const int lane = tid & 63, wv = tid >> 6;
  const int N = CC * KK;                 // 8000
  const u64* __restrict__ keys_g = cand_key + (size_t)b * N;

  __shared__ u16 candA[CC * KK];         // 16 KB
  __shared__ u16 candB[CC * KK];         // 16 KB
  __shared__ u32 whist[16][256];         // 16 KB per-wave histogram slices
  __shared__ u32 bins[256];
  __shared__ u64 smallkeys[128];
  __shared__ int ncand_s, rank_s, q_s;
  __shared__ u32 cnt_s;

  if (tid == 0) { ncand_s = N; rank_s = KK - 1; }

  u16* cur = candA;
  u16* oth = candB;
  bool first = true;
  int d = 7;
  for (;;) {
    // zero per-wave histograms
    for (int t = tid; t < 16 * 256; t += 1024) ((u32*)whist)[t] = 0;
    __syncthreads();
    const int nc = first ? N : ncand_s;
    const int sh = d * 8;
    // histogram (per-wave slices: contention capped at 64-way)
    for (int t0 = 0; t0 < nc; t0 += 1024) {
      const int t = t0 + tid;
      if (t < nc) {
        const int idx = first ? t : (int)cur[t];
        u32 dig = (u32)((keys_g[idx] >> sh) & 0xFF);
        atomicAdd(&whist[wv][dig], 1u);
      }
    }
    __syncthreads();
    // reduce slices
    if (tid < 256) {
      u32 s = 0;
      #pragma unroll
      for (int w = 0; w < 16; ++w) s += whist[w][tid];
      bins[tid] = s;
    }
    __syncthreads();
    // find target digit q (wave 0)
    if (wv == 0) {
      u32 c0 = bins[lane * 4 + 0], c1 = bins[lane * 4 + 1];
      u32 c2 = bins[lane * 4 + 2], c3 = bins[lane * 4 + 3];
      u32 lsum = c0 + c1 + c2 + c3;
      u32 incl = lsum;
      #pragma unroll
      for (int off = 1; off < 64; off <<= 1) {
        u32 v = __shfl_up(incl, off);
        if (lane >= off) incl += v;
      }
      u32 excl = incl - lsum;
      int rk = rank_s;
      u32 s0 = excl, s1 = excl + c0, s2 = s1 + c1, s3 = s2 + c2;
      int q = -1; u32 nr = 0;
      if (rk >= (int)s0 && rk < (int)(s0 + c0)) { q = lane * 4 + 0; nr = rk - s0; }
      else if (rk >= (int)s1 && rk < (int)(s1 + c1)) { q = lane * 4 + 1; nr = rk - s1; }
      else if (rk >= (int)s2 && rk < (int)(s2 + c2)) { q = lane * 4 + 2; nr = rk - s2; }
      else if (rk >= (int)s3 && rk < (int)(s3 + c3)) { q = lane * 4 + 3; nr = rk - s3; }
      if (q >= 0) { q_s = q; rank_s = (int)nr; }
    }
    if (tid == 0) cnt_s = 0;
    __syncthreads();
    // compaction, wave-aggregated (one atomic per wave per iteration)
    const int q = q_s;
    for (int t0 = 0; t0 < nc; t0 += 1024) {
      const int t = t0 + tid;
      int idx = 0; bool m = false;
      if (t < nc) {
        idx = first ? t : (int)cur[t];
        m = ((int)((keys_g[idx] >> sh) & 0xFF) == q);
      }
      u64 bal = __ballot(m);
      u32 base = 0;
      if (lane == 0 && bal) base = atomicAdd(&cnt_s, (u32)__popcll(bal));
      base = __shfl(base, 0);
      if (m) oth[base + (u32)__popcll(bal & ((1ull << lane) - 1ull))] = (u16)idx;
    }
    __syncthreads();
    if (tid == 0) ncand_s = (int)cnt_s;
    { u16* tmp = cur; cur = oth; oth = tmp; }
    first = false;
    __syncthreads();
    if (ncand_s == 1 || d == 0) break;
    --d;
  }
  const u64 T = keys_g[cur[0]];   // rank-99 smallest key (keys unique)

  // gather the exactly-100 keys <= T (wave-aggregated)
  if (tid == 0) cnt_s = 0;
  if (tid < 128) smallkeys[tid] = ~0ull;
  __syncthreads();
  for (int t0 = 0; t0 < N; t0 += 1024) {
    const int t = t0 + tid;
    u64 k = 0; bool m = false;
    if (t < N) { k = keys_g[t]; m = (k <= T); }
    u64 bal = __ballot(m);
    u32 base = 0;
    if (lane == 0 && bal) base = atomicAdd(&cnt_s, (u32)__popcll(bal));
    base = __shfl(base, 0);
    if (m) {
      u32 p = base + (u32)__popcll(bal & ((1ull << lane) - 1ull));
      if (p < 128) smallkeys[p] = k;
    }
  }
  __syncthreads();

  // hybrid bitonic sort of 128 (2 waves; LDS only for the j=64 passes)
  {
    u64 v = (tid < 128) ? smallkeys[tid] : ~0ull;
    const u32 t = (u32)tid;
    for (u32 kk = 2; kk <= 128; kk <<= 1) {
      for (u32 j = kk >> 1; j > 0; j >>= 1) {
        if (j >= 64) {
          if (tid < 128) smallkeys[t] = v;
          __syncthreads();
          u64 p = (tid < 128) ? smallkeys[t ^ j] : ~0ull;
          __syncthreads();
          if (tid < 128) {
            bool up = ((t & kk) == 0);
            bool lower = ((t & j) == 0);
            bool takemin = (up == lower);
            bool pless = (p < v);
            v = (takemin == pless) ? p : v;
          }
        } else if (tid < 128) {
          u64 p = __shfl_xor(v, (int)j);
          bool up = ((t & kk) == 0);
          bool lower = ((t & j) == 0);
          bool takemin = (up == lower);
          bool pless = (p < v);
          v = (takemin == pless) ? p : v;
        }
      }
    }
    if (tid < KK) {
      const u64 kv = v;
      const float s = sortable_to_f32(~(u32)(kv >> 32));
      float x1 = 0.f, y1 = 0.f, x2 = 0.f, y2 = 0.f, so = 0.f, cf = -1.0f;
      if (s > -5.0e8f) {                 // valid = top_s > NEG*0.5
        int c = (int)((kv >> 16) & 0xFFFFull);
        int k = (int)(kv & 0xFFFFull);
        float4 bx = cand_box[((size_t)b * CC + c) * KK + k];
        x1 = bx.x; y1 = bx.y; x2 = bx.z; y2 = bx.w;
        so = s; cf = (float)c;
      }
      float* o = out + ((size_t)b * KK + tid) * 6;
      o[0] = x1; o[1] = y1; o[2] = x2; o[3] = y2; o[4] = so; o[5] = cf;
    }
  }
}

extern "C" void kernel_launch(void* const* d_in, const int* in_sizes, int n_in,
                              void* d_out, int out_size, void* d_ws, size_t ws_size,
                              hipStream_t stream) {
  (void)in_sizes; (void)n_in; (void)out_size; (void)ws_size;
  const float* rois   = (const float*)d_in[0];
  const float* scores = (const float*)d_in[1];
  const float* deltas = (const float*)d_in[2];
  const int*   im_hw  = (const int*)d_in[3];

  u64* cand_key = (u64*)d_ws;
  float4* cand_box = (float4*)((char*)d_ws + (size_t)BB * CC * KK * sizeof(u64));

  nms_per_class<<<BB * CC, 512, 0, stream>>>(rois, scores, deltas, im_hw,
                                             cand_key, cand_box);
  topk_select<<<BB, 1024, 0, stream>>>(cand_key, cand_box, (float*)d_out);
}